// Round 1
// baseline (12200.311 us; speedup 1.0000x reference)
//
#include <hip/hip_runtime.h>
#include <cstdint>

#define DEV __device__ __forceinline__

#if __has_builtin(__builtin_amdgcn_rcpf)
DEV float rcp_fast(float x) { return __builtin_amdgcn_rcpf(x); }
#else
DEV float rcp_fast(float x) { return 1.f / x; }
#endif

// tanh(x) = 1 - 2/(exp(2x)+1): safe at +/-inf (no NaN), ~1e-7 rel err.
DEV float tanh_fast(float x) {
  float z = __expf(2.f * x);
  return 1.f - 2.f * rcp_fast(z + 1.f);
}
DEV float sigmoid_fast(float x) {
  return rcp_fast(1.f + __expf(-x));
}

// ---------------- conv0: [B,T,16] -> [B,T,64], k=5 pad=2, +bias, ReLU ------
__global__ __launch_bounds__(256) void k_conv0(
    const float* __restrict__ x, const float* __restrict__ w,
    const float* __restrict__ bias, float* __restrict__ out) {
  __shared__ float wl[16 * 5 * 64];  // [(i*5+k)*64+o] transposed for bank-free reads
  __shared__ float xl[68 * 16];
  const int blk = blockIdx.x;
  const int b = blk >> 2, tt = blk & 3;
  const int tid = threadIdx.x;
  for (int i = tid; i < 5120; i += 256) {
    int o = i / 80, rem = i % 80, ii = rem / 5, kk = rem % 5;
    wl[(ii * 5 + kk) * 64 + o] = w[i];
  }
  const int t0 = tt * 64;
  for (int i = tid; i < 68 * 16; i += 256) {
    int row = i >> 4, c = i & 15;
    int t = t0 - 2 + row;
    xl[i] = (t >= 0 && t < 256) ? x[((b << 8) + t) * 16 + c] : 0.f;
  }
  __syncthreads();
  const int o = tid & 63, tr = tid >> 6;
  for (int j = 0; j < 16; ++j) {
    int tl = tr * 16 + j;
    float acc = bias[o];
#pragma unroll
    for (int kk = 0; kk < 5; ++kk)
#pragma unroll
      for (int ii = 0; ii < 16; ++ii)
        acc += xl[(tl + kk) * 16 + ii] * wl[(ii * 5 + kk) * 64 + o];
    out[((b << 8) + t0 + tl) * 64 + o] = fmaxf(acc, 0.f);
  }
}

// ---------------- conv1: [B,T,64] -> [B,T,64], k=5 pad=2, +bias, ReLU ------
__global__ __launch_bounds__(256) void k_conv1(
    const float* __restrict__ in0, const float* __restrict__ w,
    const float* __restrict__ bias, float* __restrict__ out) {
  __shared__ float wl[64 * 5 * 64];  // 80 KB
  __shared__ float xl[68 * 64];      // 17 KB
  const int blk = blockIdx.x;
  const int b = blk >> 2, tt = blk & 3;
  const int tid = threadIdx.x;
  for (int i = tid; i < 64 * 5 * 64; i += 256) {
    int o = i / 320, rem = i % 320, ii = rem / 5, kk = rem % 5;
    wl[(ii * 5 + kk) * 64 + o] = w[i];
  }
  const int t0 = tt * 64;
  for (int i = tid; i < 68 * 64; i += 256) {
    int row = i >> 6, c = i & 63;
    int t = t0 - 2 + row;
    xl[i] = (t >= 0 && t < 256) ? in0[((b << 8) + t) * 64 + c] : 0.f;
  }
  __syncthreads();
  const int o = tid & 63, tr = tid >> 6;
  for (int j = 0; j < 16; ++j) {
    int tl = tr * 16 + j;
    float acc = bias[o];
    for (int kk = 0; kk < 5; ++kk) {
#pragma unroll 16
      for (int ii = 0; ii < 64; ++ii)
        acc += xl[(tl + kk) * 64 + ii] * wl[(ii * 5 + kk) * 64 + o];
    }
    out[((b << 8) + t0 + tl) * 64 + o] = fmaxf(acc, 0.f);
  }
}

// --------- c2e (+bias) fused with encoder input projections x@WH, x@WT -----
__global__ __launch_bounds__(256) void k_c2e_proj(
    const float* __restrict__ in1, const float* __restrict__ cw,
    const float* __restrict__ cb, const float* __restrict__ WH,
    const float* __restrict__ WT, float* __restrict__ xph,
    float* __restrict__ xpt) {
  __shared__ float xin[64 * 64];
  __shared__ float w1[64 * 64];
  __shared__ float xe[64 * 64];
  __shared__ float wh[64 * 128];
  __shared__ float wt[64 * 128];
  const int blk = blockIdx.x;
  const int b = blk >> 2, tt = blk & 3;
  const int tid = threadIdx.x;
  for (int i = tid; i < 4096; i += 256) {
    xin[i] = in1[(size_t)(((b << 8) + tt * 64)) * 64 + i];
    w1[i] = cw[i];
  }
  for (int i = tid; i < 8192; i += 256) {
    wh[i] = WH[i];
    wt[i] = WT[i];
  }
  __syncthreads();
  {
    const int o = tid & 63, tr = tid >> 6;
    for (int j = 0; j < 16; ++j) {
      int tl = tr * 16 + j;
      float acc = cb[o];
#pragma unroll 16
      for (int k = 0; k < 64; ++k) acc += xin[tl * 64 + k] * w1[k * 64 + o];
      xe[tl * 64 + o] = acc;
    }
  }
  __syncthreads();
  {
    const int m = tid & 127, hf = tid >> 7;
    for (int j = 0; j < 32; ++j) {
      int tl = hf * 32 + j;
      float a0 = 0.f, a1 = 0.f;
#pragma unroll 16
      for (int k = 0; k < 64; ++k) {
        float xv = xe[tl * 64 + k];
        a0 += xv * wh[k * 128 + m];
        a1 += xv * wt[k * 128 + m];
      }
      size_t oidx = (size_t)((b << 8) + tt * 64 + tl) * 128 + m;
      xph[oidx] = a0;
      xpt[oidx] = a1;
    }
  }
}

// ---------------- encoder RHN: one block per batch row ---------------------
// 512 threads: (g = gate, m = out column, hf = n-half). Recurrent weights in
// registers (192 VGPR/thread) -> no per-step weight traffic.
__global__ __launch_bounds__(512, 2) void k_encoder(
    const float* __restrict__ xph, const float* __restrict__ xpt,
    const float* __restrict__ RHw, const float* __restrict__ RHb,
    const float* __restrict__ RTw, const float* __restrict__ RTb,
    float* __restrict__ h_ws) {
  const int b = blockIdx.x;
  const int tid = threadIdx.x;
  const int g = tid >> 8;
  const int m = (tid >> 1) & 127;
  const int hf = tid & 1;
  const float* W = g ? RTw : RHw;
  const float* Bb = g ? RTb : RHb;
  const float* XP = g ? xpt : xph;
  float wreg[3][64];
#pragma unroll
  for (int l = 0; l < 3; ++l)
#pragma unroll
    for (int j = 0; j < 64; ++j)
      wreg[l][j] = W[(size_t)(l * 128 + hf * 64 + j) * 128 + m];
  float bias[3];
#pragma unroll
  for (int l = 0; l < 3; ++l) bias[l] = Bb[l * 128 + m];

  __shared__ float s_lds[128];
  __shared__ float hg[128];
  __shared__ float tg[128];
  if (tid < 128) s_lds[tid] = 0.f;
  __syncthreads();

  for (int t = 0; t < 256; ++t) {
    const float xp = XP[(size_t)((b << 8) + t) * 128 + m];
#pragma unroll
    for (int l = 0; l < 3; ++l) {
      float acc = (hf == 0) ? (bias[l] + (l == 0 ? xp : 0.f)) : 0.f;
      const float* sp = s_lds + hf * 64;
#pragma unroll
      for (int j = 0; j < 64; ++j) acc += sp[j] * wreg[l][j];
      float tot = acc + __shfl_xor(acc, 1);
      if (hf == 0) {
        if (g == 0) hg[m] = tanh_fast(tot);
        else        tg[m] = sigmoid_fast(tot);
      }
      __syncthreads();
      if (tid < 128) {
        float tv = tg[tid];
        float sn = hg[tid] * tv + (1.f - tv) * s_lds[tid];
        s_lds[tid] = sn;
        h_ws[((size_t)(b * 3 + l) * 256 + t) * 128 + tid] = sn;  // [B][RD][T][NE]
      }
      __syncthreads();
    }
  }
}

// ---------------- Uh[b][r][t][m] = h[b][r][t][:] @ Uk_w[r] + Uk_b[r] -------
__global__ __launch_bounds__(256) void k_uh(
    const float* __restrict__ h_ws, const float* __restrict__ Uk_w,
    const float* __restrict__ Uk_b, float* __restrict__ Uh) {
  __shared__ float wl[128 * 128];  // 64 KB
  __shared__ float hl[32 * 128];   // 16 KB
  const int blk = blockIdx.x;
  const int b = blk / 24;
  const int rem = blk % 24;
  const int r = rem >> 3, tt = rem & 7;
  const int tid = threadIdx.x;
  for (int i = tid; i < 16384; i += 256) wl[i] = Uk_w[(size_t)r * 16384 + i];
  const size_t hbase = ((size_t)(b * 3 + r) * 256 + tt * 32) * 128;
  for (int i = tid; i < 4096; i += 256) hl[i] = h_ws[hbase + i];
  __syncthreads();
  const int m = tid & 127, tr = tid >> 7;
  const float ub = Uk_b[r * 128 + m];
  for (int j = 0; j < 16; ++j) {
    int tl = tr * 16 + j;
    float acc = ub;
#pragma unroll 16
    for (int n = 0; n < 128; ++n) acc += hl[tl * 128 + n] * wl[n * 128 + m];
    Uh[hbase + (size_t)tl * 128 + m] = acc;
  }
}

// ---------------- attentive RHN decoder: one block per batch row -----------
// 768 threads; Tk_w hoisted to registers. Per step: Ts -> e (tanh dot) ->
// softmax over T -> d -> y_til -> 3-micro-step RHN cell. Final linear head.
__global__ __launch_bounds__(768, 3) void k_decoder(
    const float* __restrict__ y, const float* __restrict__ Uh,
    const float* __restrict__ h_ws, const float* __restrict__ Tk_w,
    const float* __restrict__ vk_w, const float* __restrict__ vk_b,
    const float* __restrict__ Wt_w, const float* __restrict__ Vt_w,
    const float* __restrict__ Vt_b,
    const float* __restrict__ WHd, const float* __restrict__ WTd,
    const float* __restrict__ RHw, const float* __restrict__ RHb,
    const float* __restrict__ RTw, const float* __restrict__ RTb,
    const float* __restrict__ W_w, const float* __restrict__ W_b,
    const float* __restrict__ V_w, const float* __restrict__ V_b,
    float* __restrict__ out) {
  const int b = blockIdx.x;
  const int tid = threadIdx.x;
  __shared__ float s_lds[128];
  __shared__ float Ts_lds[384];
  __shared__ float a_lds[768];   // e scores, then alpha
  __shared__ float d_lds[384];
  __shared__ float vk_lds[384];
  __shared__ float Vt_lds[384];
  __shared__ float hg[128];
  __shared__ float tg[128];
  __shared__ float red[32];
  __shared__ float ytil_lds;

  const int r3 = tid >> 8;          // 0..2
  const int m2 = (tid >> 1) & 127;
  const int p2 = tid & 1;           // pair-split (n-half / t-half)
  float tk[64];
#pragma unroll
  for (int j = 0; j < 64; ++j)
    tk[j] = Tk_w[(size_t)(r3 * 128 + p2 * 64 + j) * 128 + m2];

  for (int i = tid; i < 384; i += 768) {
    vk_lds[i] = vk_w[i];
    Vt_lds[i] = Vt_w[i];
  }
  if (tid < 128) s_lds[tid] = 0.f;
  __syncthreads();

  const int t_e = tid & 255;
  const float vkb = vk_b[r3];
  const int wv = tid >> 6;  // wave 0..11 (aligned: 4 waves per r)
  const int lane = tid & 63;

  for (int step = 0; step < 256; ++step) {
    // ---- Ts[r][m] = s @ Tk_w[r] ----
    {
      float acc = 0.f;
      const float* sp = s_lds + p2 * 64;
#pragma unroll
      for (int j = 0; j < 64; ++j) acc += sp[j] * tk[j];
      float tot = acc + __shfl_xor(acc, 1);
      if (p2 == 0) Ts_lds[r3 * 128 + m2] = tot;
    }
    __syncthreads();
    // ---- e[r][t] = vk . tanh(Uh + Ts) + vk_b ----
    {
      const float4* ub =
          (const float4*)(Uh + ((size_t)(b * 3 + r3) * 256 + t_e) * 128);
      const float* tsp = Ts_lds + r3 * 128;
      const float* vkp = vk_lds + r3 * 128;
      float acc = 0.f;
#pragma unroll 8
      for (int q = 0; q < 32; ++q) {
        float4 u = ub[q];
        acc += vkp[4 * q + 0] * tanh_fast(u.x + tsp[4 * q + 0]);
        acc += vkp[4 * q + 1] * tanh_fast(u.y + tsp[4 * q + 1]);
        acc += vkp[4 * q + 2] * tanh_fast(u.z + tsp[4 * q + 2]);
        acc += vkp[4 * q + 3] * tanh_fast(u.w + tsp[4 * q + 3]);
      }
      a_lds[r3 * 256 + t_e] = acc + vkb;
    }
    __syncthreads();
    // ---- softmax over t (per r) ----
    {
      float e = a_lds[r3 * 256 + t_e];
      float mx = e;
#pragma unroll
      for (int off = 32; off; off >>= 1) mx = fmaxf(mx, __shfl_xor(mx, off));
      if (lane == 0) red[wv] = mx;
      __syncthreads();
      const int wb = r3 * 4;
      mx = fmaxf(fmaxf(red[wb], red[wb + 1]), fmaxf(red[wb + 2], red[wb + 3]));
      float p = __expf(e - mx);
      float sm = p;
#pragma unroll
      for (int off = 32; off; off >>= 1) sm += __shfl_xor(sm, off);
      if (lane == 0) red[16 + wv] = sm;
      __syncthreads();
      float den =
          red[16 + wb] + red[16 + wb + 1] + red[16 + wb + 2] + red[16 + wb + 3];
      a_lds[r3 * 256 + t_e] = p * rcp_fast(den);
    }
    __syncthreads();
    // ---- d[r][m] = sum_t alpha[r][t] * h[b][r][t][m] ----
    {
      const float* hp =
          h_ws + ((size_t)(b * 3 + r3) * 256 + p2 * 128) * 128 + m2;
      const float* ap = a_lds + r3 * 256 + p2 * 128;
      float acc = 0.f;
#pragma unroll 4
      for (int t2 = 0; t2 < 128; ++t2) acc += ap[t2] * hp[(size_t)t2 * 128];
      float tot = acc + __shfl_xor(acc, 1);
      if (p2 == 0) d_lds[r3 * 128 + m2] = tot;
    }
    __syncthreads();
    // ---- y_til = y_t*Wt + d.Vt_w + Vt_b ----
    {
      float part = (tid < 384) ? d_lds[tid] * Vt_lds[tid] : 0.f;
#pragma unroll
      for (int off = 32; off; off >>= 1) part += __shfl_xor(part, off);
      if (lane == 0) red[wv] = part;
      __syncthreads();
      if (tid == 0) {
        float tot = red[0] + red[1] + red[2] + red[3] + red[4] + red[5];
        ytil_lds = y[(b << 8) + step] * Wt_w[0] + tot + Vt_b[0];
      }
      __syncthreads();
    }
    // ---- decoder RHN cell (3 micro-steps) ----
    {
      const float ytil = ytil_lds;
#pragma unroll
      for (int l = 0; l < 3; ++l) {
        if (tid < 256) {
          const int g = tid >> 7, m = tid & 127;
          const float* W = (g ? RTw : RHw) + (size_t)(l * 128) * 128 + m;
          float acc = (g ? RTb : RHb)[l * 128 + m];
          if (l == 0) acc += ytil * (g ? WTd : WHd)[m];
#pragma unroll 8
          for (int n = 0; n < 128; ++n) acc += s_lds[n] * W[(size_t)n * 128];
          if (g == 0) hg[m] = tanh_fast(acc);
          else        tg[m] = sigmoid_fast(acc);
        }
        __syncthreads();
        if (tid < 128) {
          float tv = tg[tid];
          s_lds[tid] = hg[tid] * tv + (1.f - tv) * s_lds[tid];
        }
        __syncthreads();
      }
    }
  }
  // ---- output head: out[b] = s.W_w + W_b + d.V_w + V_b ----
  if (tid < 64) {
    float acc = 0.f;
    for (int i = tid; i < 128; i += 64) acc += s_lds[i] * W_w[i];
    for (int k = tid; k < 384; k += 64) acc += d_lds[k] * V_w[k];
#pragma unroll
    for (int off = 32; off; off >>= 1) acc += __shfl_xor(acc, off);
    if (tid == 0) out[b] = acc + W_b[0] + V_b[0];
  }
}

extern "C" void kernel_launch(void* const* d_in, const int* in_sizes, int n_in,
                              void* d_out, int out_size, void* d_ws,
                              size_t ws_size, hipStream_t stream) {
  (void)in_sizes; (void)n_in; (void)out_size; (void)ws_size;
  const float* x    = (const float*)d_in[0];
  const float* y    = (const float*)d_in[1];
  const float* c0w  = (const float*)d_in[2];
  const float* c0b  = (const float*)d_in[3];
  const float* c1w  = (const float*)d_in[4];
  const float* c1b  = (const float*)d_in[5];
  const float* c2ew = (const float*)d_in[6];
  const float* c2eb = (const float*)d_in[7];
  const float* eWH  = (const float*)d_in[8];
  const float* eWT  = (const float*)d_in[9];
  const float* eRHw = (const float*)d_in[10];
  const float* eRHb = (const float*)d_in[11];
  const float* eRTw = (const float*)d_in[12];
  const float* eRTb = (const float*)d_in[13];
  const float* dWH  = (const float*)d_in[14];
  const float* dWT  = (const float*)d_in[15];
  const float* dRHw = (const float*)d_in[16];
  const float* dRHb = (const float*)d_in[17];
  const float* dRTw = (const float*)d_in[18];
  const float* dRTb = (const float*)d_in[19];
  const float* Tk   = (const float*)d_in[20];
  const float* Ukw  = (const float*)d_in[21];
  const float* Ukb  = (const float*)d_in[22];
  const float* vkw  = (const float*)d_in[23];
  const float* vkb  = (const float*)d_in[24];
  const float* Wtw  = (const float*)d_in[25];
  const float* Vtw  = (const float*)d_in[26];
  const float* Vtb  = (const float*)d_in[27];
  const float* Ww   = (const float*)d_in[28];
  const float* Wb   = (const float*)d_in[29];
  const float* Vw   = (const float*)d_in[30];
  const float* Vb   = (const float*)d_in[31];
  float* out = (float*)d_out;
  float* ws = (float*)d_ws;

  // Workspace layout (floats). Total 50,331,648 floats = 201.3 MB.
  // h lives at [0, 25.2M); Uh at [25.2M, 50.3M). xph/xpt/conv buffers alias
  // the Uh region (they are dead before k_uh writes Uh).
  float* h_ws = ws;
  float* Uh   = ws + 25165824;
  float* xph  = Uh;
  float* xpt  = Uh + 8388608;
  float* c0o  = Uh + 16777216;
  float* c1o  = Uh + 20971520;

  k_conv0<<<1024, 256, 0, stream>>>(x, c0w, c0b, c0o);
  k_conv1<<<1024, 256, 0, stream>>>(c0o, c1w, c1b, c1o);
  k_c2e_proj<<<1024, 256, 0, stream>>>(c1o, c2ew, c2eb, eWH, eWT, xph, xpt);
  k_encoder<<<256, 512, 0, stream>>>(xph, xpt, eRHw, eRHb, eRTw, eRTb, h_ws);
  k_uh<<<6144, 256, 0, stream>>>(h_ws, Ukw, Ukb, Uh);
  k_decoder<<<256, 768, 0, stream>>>(y, Uh, h_ws, Tk, vkw, vkb, Wtw, Vtw, Vtb,
                                     dWH, dWT, dRHw, dRHb, dRTw, dRTb,
                                     Ww, Wb, Vw, Vb, out);
}